// Round 1
// baseline (345.051 us; speedup 1.0000x reference)
//
#include <hip/hip_runtime.h>

// Retrace loss: per-row backward affine recurrence solved with a block-level
// affine-map scan (one block per row, 256 threads x 16 elements), then
// mean-squared-error reduction. Memory-bound: 6 x 64MiB fp32 reads.

#define NROWS 4096
#define TLEN  4096
#define BLOCK 256
#define EPT   16

__global__ __launch_bounds__(BLOCK) void retrace_main(
    const float* __restrict__ Q,
    const float* __restrict__ eQ,
    const float* __restrict__ tQ,
    const float* __restrict__ rw,
    const float* __restrict__ tpp,
    const float* __restrict__ bpp,
    double* __restrict__ partials)
{
    constexpr float G = 0.99f;
    __shared__ float sA[BLOCK];
    __shared__ float sB[BLOCK];
    __shared__ float sRed[BLOCK / 64];

    const int tid = threadIdx.x;
    const long long base = (long long)blockIdx.x * TLEN;
    // thread tid handles s in [16*tid, 16*tid+16), s = T-1-t (backward index)
    // aligned chunk base in element space: covers t/u windows for this thread
    const int ua = (TLEN - EPT) - EPT * tid;   // 4080 - 16*tid, 64B aligned

    // m-indexed per-thread state, m in [1,16]; k = 16 - m is the local scan step.
    // A[s] = G*c[u], B[s] = 100*r[t] + G*(eq[u] - c[u]*tq[u]),  u = t+1 = ua+m (m: k=16-m)
    float Aa[17], Bb[17];

    float prev_r = 0.0f;
    #pragma unroll
    for (int g = 0; g < 4; ++g) {
        const float4 r4 = *(const float4*)(rw  + base + ua + 4 * g);
        const float4 t4 = *(const float4*)(tpp + base + ua + 4 * g);
        const float4 p4 = *(const float4*)(bpp + base + ua + 4 * g);
        const float4 q4 = *(const float4*)(tQ  + base + ua + 4 * g);
        const float4 e4 = *(const float4*)(eQ  + base + ua + 4 * g);
        const float rv[4] = {r4.x, r4.y, r4.z, r4.w};
        const float tv[4] = {t4.x, t4.y, t4.z, t4.w};
        const float pv[4] = {p4.x, p4.y, p4.z, p4.w};
        const float qv[4] = {q4.x, q4.y, q4.z, q4.w};
        const float ev[4] = {e4.x, e4.y, e4.z, e4.w};
        #pragma unroll
        for (int e = 0; e < 4; ++e) {
            const int m = 4 * g + e;
            if (m >= 1) {
                const float c  = __expf(fminf(tv[e] - pv[e], 0.0f));
                const float gc = G * c;
                const float f  = fmaf(-gc, qv[e], G * ev[e]);
                const float rp = (e == 0) ? prev_r : rv[e - 1];
                Aa[m] = gc;
                Bb[m] = fmaf(100.0f, rp, f);
            }
        }
        prev_r = rv[3];
    }
    // m = 16 element (k = 0). For tid 0 this is s = 0: y = tQ[T-1] exactly.
    if (tid == 0) {
        Aa[16] = 0.0f;
        Bb[16] = tQ[base + TLEN - 1];
    } else {
        const float tx = tpp[base + ua + 16];
        const float px = bpp[base + ua + 16];
        const float qx = tQ [base + ua + 16];
        const float ex = eQ [base + ua + 16];
        const float c  = __expf(fminf(tx - px, 0.0f));
        const float gc = G * c;
        const float f  = fmaf(-gc, qx, G * ex);
        Aa[16] = gc;
        Bb[16] = fmaf(100.0f, prev_r, f);
    }

    // Local sequential composite over this thread's 16 affine maps (k ascending).
    float Ac = 1.0f, Bc = 0.0f;
    #pragma unroll
    for (int k = 0; k < EPT; ++k) {
        const int m = 16 - k;
        Bc = fmaf(Aa[m], Bc, Bb[m]);
        Ac = Aa[m] * Ac;
    }

    // Hillis-Steele inclusive scan of affine maps across the block.
    sA[tid] = Ac; sB[tid] = Bc;
    __syncthreads();
    #pragma unroll
    for (int off = 1; off < BLOCK; off <<= 1) {
        float a1 = 0.0f, b1 = 0.0f;
        const bool has = (tid >= off);
        if (has) { a1 = sA[tid - off]; b1 = sB[tid - off]; }
        const float a2 = sA[tid], b2 = sB[tid];
        __syncthreads();
        if (has) { sA[tid] = a2 * a1; sB[tid] = fmaf(a2, b1, b2); }
        __syncthreads();
    }
    // Exclusive prefix: chunk 0 contains s=0 whose A=0, so inclusive[j-1].A == 0
    // exactly; the incoming value is just inclusive[j-1].B.
    float y = (tid == 0) ? 0.0f : sB[tid - 1];

    // Apply the recurrence locally and accumulate squared error against Q.
    float qq[16];
    #pragma unroll
    for (int g = 0; g < 4; ++g) {
        const float4 Q4 = *(const float4*)(Q + base + ua + 4 * g);
        qq[4 * g + 0] = Q4.x; qq[4 * g + 1] = Q4.y;
        qq[4 * g + 2] = Q4.z; qq[4 * g + 3] = Q4.w;
    }
    float acc = 0.0f;
    #pragma unroll
    for (int k = 0; k < EPT; ++k) {
        const int m = 16 - k;
        y = fmaf(Aa[m], y, Bb[m]);          // y = Q_ret[t], t = ua + m - 1
        const float d = qq[m - 1] - y;      // Q[t] - Q_ret[t]
        acc = fmaf(d, d, acc);
    }

    // Block reduction: wave=64 shuffle, then tiny LDS combine.
    #pragma unroll
    for (int off = 32; off > 0; off >>= 1)
        acc += __shfl_down(acc, off, 64);
    if ((tid & 63) == 0) sRed[tid >> 6] = acc;
    __syncthreads();
    if (tid == 0) {
        const float s = sRed[0] + sRed[1] + sRed[2] + sRed[3];
        partials[blockIdx.x] = (double)s;   // every block writes its slot -> poison-safe
    }
}

__global__ __launch_bounds__(BLOCK) void retrace_finalize(
    const double* __restrict__ partials, float* __restrict__ out)
{
    __shared__ double sRed[BLOCK / 64];
    double s = 0.0;
    for (int i = threadIdx.x; i < NROWS; i += BLOCK) s += partials[i];
    #pragma unroll
    for (int off = 32; off > 0; off >>= 1)
        s += __shfl_down(s, off, 64);
    if ((threadIdx.x & 63) == 0) sRed[threadIdx.x >> 6] = s;
    __syncthreads();
    if (threadIdx.x == 0) {
        const double tot = sRed[0] + sRed[1] + sRed[2] + sRed[3];
        out[0] = (float)(tot / ((double)NROWS * (double)TLEN));
    }
}

extern "C" void kernel_launch(void* const* d_in, const int* in_sizes, int n_in,
                              void* d_out, int out_size, void* d_ws, size_t ws_size,
                              hipStream_t stream)
{
    // setup_inputs order: Q, expected_target_Q, target_Q, rewards,
    //                     target_policy_probs, behaviour_policy_probs
    const float* Q   = (const float*)d_in[0];
    const float* eQ  = (const float*)d_in[1];
    const float* tQ  = (const float*)d_in[2];
    const float* rw  = (const float*)d_in[3];
    const float* tpp = (const float*)d_in[4];
    const float* bpp = (const float*)d_in[5];
    double* partials = (double*)d_ws;       // 4096 doubles = 32 KB scratch

    retrace_main<<<NROWS, BLOCK, 0, stream>>>(Q, eQ, tQ, rw, tpp, bpp, partials);
    retrace_finalize<<<1, BLOCK, 0, stream>>>(partials, (float*)d_out);
}

// Round 2
// 339.746 us; speedup vs baseline: 1.0156x; 1.0156x over previous
//
#include <hip/hip_runtime.h>

// Retrace loss: per-row backward affine recurrence y[s] = A[s]*y[s-1] + B[s],
// solved with a shuffle-based affine-map scan. One block per row, 256 threads
// x 16 elements. All 6 input arrays prefetched up-front (24 float4 loads in
// flight before any compute); scan uses wave shuffles (no barriers) + a
// 4-entry LDS cross-wave combine (2 barriers total per block).
// Memory-bound: 6 x 64MiB fp32 reads, ~64us HBM floor.

#define NROWS 4096
#define TLEN  4096
#define BLOCK 256
#define EPT   16

__global__ __launch_bounds__(BLOCK) void retrace_main(
    const float* __restrict__ Q,
    const float* __restrict__ eQ,
    const float* __restrict__ tQ,
    const float* __restrict__ rw,
    const float* __restrict__ tpp,
    const float* __restrict__ bpp,
    double* __restrict__ partials)
{
    constexpr float G = 0.99f;
    __shared__ float sWA[4], sWB[4];
    __shared__ float sRed[4];

    const int tid  = threadIdx.x;
    const int lane = tid & 63;
    const int wv   = tid >> 6;
    const long long base = (long long)blockIdx.x * TLEN;
    // thread tid handles backward indices s in [16*tid, 16*tid+16);
    // its 64B-aligned element window starts at ua (covers t and u=t+1 needs).
    const int ua = (TLEN - EPT) - EPT * tid;   // 4080 - 16*tid

    // ---- Prefetch: issue ALL global loads before any compute/sync ----
    float4 Rv4[4], Tv4[4], Pv4[4], Qt4[4], Ev4[4], Qm4[4];
    #pragma unroll
    for (int g = 0; g < 4; ++g) Rv4[g] = *(const float4*)(rw  + base + ua + 4 * g);
    #pragma unroll
    for (int g = 0; g < 4; ++g) Tv4[g] = *(const float4*)(tpp + base + ua + 4 * g);
    #pragma unroll
    for (int g = 0; g < 4; ++g) Pv4[g] = *(const float4*)(bpp + base + ua + 4 * g);
    #pragma unroll
    for (int g = 0; g < 4; ++g) Qt4[g] = *(const float4*)(tQ  + base + ua + 4 * g);
    #pragma unroll
    for (int g = 0; g < 4; ++g) Ev4[g] = *(const float4*)(eQ  + base + ua + 4 * g);
    #pragma unroll
    for (int g = 0; g < 4; ++g) Qm4[g] = *(const float4*)(Q   + base + ua + 4 * g);

    // Wave-boundary threads (64,128,192) can't shuffle from the previous wave:
    // load their shifted-window (index ua+16) scalars from global (L1/L2 hit).
    const bool bnd = (lane == 0) && (tid != 0);
    float bt = 0.f, bp = 0.f, bq = 0.f, be = 0.f;
    if (bnd) {
        bt = tpp[base + ua + 16];
        bp = bpp[base + ua + 16];
        bq = tQ [base + ua + 16];
        be = eQ [base + ua + 16];
    }

    // Flatten for indexed access (register arrays, fully unrolled use).
    float rv[16], tv[16], pv[16], qv[16], ev[16], qm[16];
    #pragma unroll
    for (int g = 0; g < 4; ++g) {
        rv[4*g+0]=Rv4[g].x; rv[4*g+1]=Rv4[g].y; rv[4*g+2]=Rv4[g].z; rv[4*g+3]=Rv4[g].w;
        tv[4*g+0]=Tv4[g].x; tv[4*g+1]=Tv4[g].y; tv[4*g+2]=Tv4[g].z; tv[4*g+3]=Tv4[g].w;
        pv[4*g+0]=Pv4[g].x; pv[4*g+1]=Pv4[g].y; pv[4*g+2]=Pv4[g].z; pv[4*g+3]=Pv4[g].w;
        qv[4*g+0]=Qt4[g].x; qv[4*g+1]=Qt4[g].y; qv[4*g+2]=Qt4[g].z; qv[4*g+3]=Qt4[g].w;
        ev[4*g+0]=Ev4[g].x; ev[4*g+1]=Ev4[g].y; ev[4*g+2]=Ev4[g].z; ev[4*g+3]=Ev4[g].w;
        qm[4*g+0]=Qm4[g].x; qm[4*g+1]=Qm4[g].y; qm[4*g+2]=Qm4[g].z; qm[4*g+3]=Qm4[g].w;
    }

    // ---- Build the 16 affine maps (index idx = m-1, m in [1,16]) ----
    // Map m: A = G*c[u], B = 100*r[u-1] + G*(eq[u] - c[u]*tq[u]), u = ua+m.
    float Aa[16], Bb[16];
    #pragma unroll
    for (int m = 1; m <= 15; ++m) {
        const float c  = __expf(fminf(tv[m] - pv[m], 0.0f));
        const float gc = G * c;
        const float f  = fmaf(-gc, qv[m], G * ev[m]);
        Aa[m-1] = gc;
        Bb[m-1] = fmaf(100.0f, rv[m-1], f);
    }
    // m = 16: shifted-window element at ua+16 == neighbor thread's m=0 element.
    {
        float t16 = __shfl_up(tv[0], 1, 64);
        float p16 = __shfl_up(pv[0], 1, 64);
        float q16 = __shfl_up(qv[0], 1, 64);
        float e16 = __shfl_up(ev[0], 1, 64);
        if (bnd) { t16 = bt; p16 = bp; q16 = bq; e16 = be; }
        if (tid == 0) {
            // s = 0: y = tQ[T-1] exactly (A = 0 kills any prior state).
            Aa[15] = 0.0f;
            Bb[15] = qv[15];            // tQ[base + 4095] is this thread's last element
        } else {
            const float c  = __expf(fminf(t16 - p16, 0.0f));
            const float gc = G * c;
            const float f  = fmaf(-gc, q16, G * e16);
            Aa[15] = gc;
            Bb[15] = fmaf(100.0f, rv[15], f);
        }
    }

    // ---- Local sequential composite (maps applied idx = 15 down to 0) ----
    float Ac = 1.0f, Bc = 0.0f;
    #pragma unroll
    for (int k = 0; k < EPT; ++k) {
        const int idx = 15 - k;
        Bc = fmaf(Aa[idx], Bc, Bb[idx]);
        Ac = Aa[idx] * Ac;
    }

    // ---- Wave-level inclusive scan of affine maps (no barriers) ----
    float Ai = Ac, Bi = Bc;
    #pragma unroll
    for (int off = 1; off < 64; off <<= 1) {
        const float Ap = __shfl_up(Ai, off, 64);
        const float Bp = __shfl_up(Bi, off, 64);
        if (lane >= off) {
            Bi = fmaf(Ai, Bp, Bi);
            Ai = Ai * Ap;
        }
    }

    // ---- Cross-wave combine: 4 wave composites through LDS ----
    if (lane == 63) { sWA[wv] = Ai; sWB[wv] = Bi; }
    __syncthreads();
    // Incoming state for this wave = composite of waves 0..wv-1 applied to y0=0.
    // (That composite's A is exactly 0 for wv>=1 since thread 0 holds the s=0
    //  map with A=0 — only the B component survives.)
    float Bp = 0.0f;
    #pragma unroll
    for (int j = 0; j < 3; ++j)
        if (j < wv) Bp = fmaf(sWA[j], Bp, sWB[j]);

    // Exclusive-within-wave prefix, then compose with incoming wave state.
    float Ae = __shfl_up(Ai, 1, 64);
    float Be = __shfl_up(Bi, 1, 64);
    if (lane == 0) { Ae = 1.0f; Be = 0.0f; }
    float y = fmaf(Ae, Bp, Be);            // y entering this thread's chunk

    // ---- Apply maps locally + accumulate squared error vs Q ----
    float acc = 0.0f;
    #pragma unroll
    for (int k = 0; k < EPT; ++k) {
        const int idx = 15 - k;
        y = fmaf(Aa[idx], y, Bb[idx]);     // y = Q_ret[t], t = ua + idx
        const float d = qm[idx] - y;
        acc = fmaf(d, d, acc);
    }

    // ---- Block reduction: wave shuffle (width 64) + tiny LDS combine ----
    #pragma unroll
    for (int off = 32; off > 0; off >>= 1)
        acc += __shfl_down(acc, off, 64);
    if (lane == 0) sRed[wv] = acc;
    __syncthreads();
    if (tid == 0) {
        const float s = sRed[0] + sRed[1] + sRed[2] + sRed[3];
        partials[blockIdx.x] = (double)s;  // every block writes its slot -> poison-safe
    }
}

__global__ __launch_bounds__(BLOCK) void retrace_finalize(
    const double* __restrict__ partials, float* __restrict__ out)
{
    __shared__ double sRed[BLOCK / 64];
    double s = 0.0;
    for (int i = threadIdx.x; i < NROWS; i += BLOCK) s += partials[i];
    #pragma unroll
    for (int off = 32; off > 0; off >>= 1)
        s += __shfl_down(s, off, 64);
    if ((threadIdx.x & 63) == 0) sRed[threadIdx.x >> 6] = s;
    __syncthreads();
    if (threadIdx.x == 0) {
        const double tot = sRed[0] + sRed[1] + sRed[2] + sRed[3];
        out[0] = (float)(tot / ((double)NROWS * (double)TLEN));
    }
}

extern "C" void kernel_launch(void* const* d_in, const int* in_sizes, int n_in,
                              void* d_out, int out_size, void* d_ws, size_t ws_size,
                              hipStream_t stream)
{
    // setup_inputs order: Q, expected_target_Q, target_Q, rewards,
    //                     target_policy_probs, behaviour_policy_probs
    const float* Q   = (const float*)d_in[0];
    const float* eQ  = (const float*)d_in[1];
    const float* tQ  = (const float*)d_in[2];
    const float* rw  = (const float*)d_in[3];
    const float* tpp = (const float*)d_in[4];
    const float* bpp = (const float*)d_in[5];
    double* partials = (double*)d_ws;       // 4096 doubles = 32 KB scratch

    retrace_main<<<NROWS, BLOCK, 0, stream>>>(Q, eQ, tQ, rw, tpp, bpp, partials);
    retrace_finalize<<<1, BLOCK, 0, stream>>>(partials, (float*)d_out);
}